// Round 7
// baseline (113.170 us; speedup 1.0000x reference)
//
#include <hip/hip_runtime.h>

// EdgeCompute v15: LDS-FREE register-direct gather in MFMA B-fragment layout.
// out = sigmoid( relu(|x[s]-x[d]| @ W1 + b1) @ W2 + b2 )
// N_EDGES=640000, D_FEAT=128, HID=64.
//
// R6 lessons: pre-warm null -> gather is SELF-warming (xh = 20k lines
// referenced 128x each; L2 warm after ~2% of kernel). T_edge ~24.5us at
// any schedule/occupancy tried. Largest removable component: the LDS
// transpose round-trip (48 ds_b128/wave-tile ~ 576cyc) used only to get
// gathered rows into B-fragment layout. But B-frag IS directly loadable:
// lane l holds halfs k=(l>>4)*8..+7 of edge l&15 -> load 16B from
// xh[id(l&15)]*128 + kb*32 + (l>>4)*8. v15: ids via 2 shfl, 8 loads,
// reg diff, 16 MFMA per 16-edge batch. kb-pairs share a 128B line (L1
// absorbs ~half of L2 requests). Zero LDS -> launch_bounds(256,3)
// (3 waves/SIMD, +50% TLP). Dropped pre-warm + idx-warm (proven null).
// Predict: T_edge 24.5 -> 14-17us, dur 95.4 -> ~86-89, absmax 0.0039.
// Null => service-rate-pinned + harness-dominated; declare roofline.

#define DF 128
#define HID 64

typedef _Float16 half8   __attribute__((ext_vector_type(8)));
typedef _Float16 half4_t __attribute__((ext_vector_type(4)));
typedef float    floatx4 __attribute__((ext_vector_type(4)));

__device__ __forceinline__ float sigmoidf_(float t) {
    return __builtin_amdgcn_rcpf(1.0f + __expf(-t));
}

// pre-pass: x -> f16 (2.56MB, L2-resident), W1 -> f16 transposed [hid][feat]
__global__ void cvt_pre(const float* __restrict__ x, const float* __restrict__ W1,
                        _Float16* __restrict__ xh, _Float16* __restrict__ w1t, int n4)
{
    const int i = blockIdx.x * blockDim.x + threadIdx.x;
    if (i < n4) {
        float4 v = ((const float4*)x)[i];
        half4_t h = { (_Float16)v.x, (_Float16)v.y, (_Float16)v.z, (_Float16)v.w };
        ((half4_t*)xh)[i] = h;
    }
    if (i < DF * HID) {                      // w1t[h*128+f] = W1[f*64+h]
        const int h = i >> 7, f = i & 127;
        w1t[i] = (_Float16)W1[f * HID + h];
    }
}

__global__ __launch_bounds__(256, 3) void edge_mlp_v15(
    const _Float16* __restrict__ xh, const _Float16* __restrict__ w1t,
    const int* __restrict__ idx,
    const float* __restrict__ b1, const float* __restrict__ W2,
    const float* __restrict__ b2,
    float* __restrict__ out, int n_edges, int ngroups, int gstride)
{
    const int tid = threadIdx.x;
    const int L   = tid & 63;
    const int r16 = L & 15;                 // edge-in-batch / B-frag column
    const int q   = L >> 4;                 // k-chunk (q*8 halfs) / A-frag k + C row-group
    const int wv  = tid >> 6;

    // ---- A fragments: W1^T [hid=mt*16+r16][k=kb*32+q*8+j] (64 VGPRs) ----
    half8 wf[4][4];
#pragma unroll
    for (int mt = 0; mt < 4; ++mt)
#pragma unroll
        for (int kb = 0; kb < 4; ++kb)
            wf[mt][kb] = *(const half8*)(w1t + (size_t)(mt * 16 + r16) * DF + kb * 32 + q * 8);
#pragma unroll
    for (int mt = 0; mt < 4; ++mt)
#pragma unroll
        for (int kb = 0; kb < 4; ++kb)
            asm volatile("" : "+v"(wf[mt][kb]));

    // epilogue constants at hid = mt*16 + q*4 + r (f16-packed, 8 VGPRs)
    half4_t b1h[4], w2h[4];
#pragma unroll
    for (int mt = 0; mt < 4; ++mt)
#pragma unroll
        for (int r = 0; r < 4; ++r) {
            b1h[mt][r] = (_Float16)b1[mt * 16 + q * 4 + r];
            w2h[mt][r] = (_Float16)W2[mt * 16 + q * 4 + r];
        }
    const float b2v = b2[0];

    const int g0 = blockIdx.x;

#pragma unroll 1
    for (int g = g0; g < ngroups; g += gstride) {
        const int ebase = g * 256 + wv * 64;

        // wave's 64 edge ids, one coalesced dword per lane
        const int sAll = idx[ebase + L];
        const int dAll = idx[n_edges + ebase + L];

#pragma unroll
        for (int bt = 0; bt < 4; ++bt) {
            // broadcast batch ids: edge (l&15) of batch bt lives in lane bt*16+(l&15)
            const int se = __shfl(sAll, bt * 16 + r16, 64);
            const int de = __shfl(dAll, bt * 16 + r16, 64);
            const _Float16* sp = xh + (size_t)se * DF + q * 8;
            const _Float16* dp = xh + (size_t)de * DF + q * 8;

            // direct B-fragment loads: 16B per lane per kb; kb pairs share a 128B line
            half8 s0 = *(const half8*)(sp +  0);
            half8 s1 = *(const half8*)(sp + 32);
            half8 s2 = *(const half8*)(sp + 64);
            half8 s3 = *(const half8*)(sp + 96);
            half8 d0 = *(const half8*)(dp +  0);
            half8 d1 = *(const half8*)(dp + 32);
            half8 d2 = *(const half8*)(dp + 64);
            half8 d3 = *(const half8*)(dp + 96);

            // |s - d| in registers (packed f16 sub + abs mask)
            union { half8 h; uint4 u; } B0, B1, B2, B3;
            B0.h = s0 - d0; B1.h = s1 - d1; B2.h = s2 - d2; B3.h = s3 - d3;
            B0.u.x &= 0x7FFF7FFFu; B0.u.y &= 0x7FFF7FFFu;
            B0.u.z &= 0x7FFF7FFFu; B0.u.w &= 0x7FFF7FFFu;
            B1.u.x &= 0x7FFF7FFFu; B1.u.y &= 0x7FFF7FFFu;
            B1.u.z &= 0x7FFF7FFFu; B1.u.w &= 0x7FFF7FFFu;
            B2.u.x &= 0x7FFF7FFFu; B2.u.y &= 0x7FFF7FFFu;
            B2.u.z &= 0x7FFF7FFFu; B2.u.w &= 0x7FFF7FFFu;
            B3.u.x &= 0x7FFF7FFFu; B3.u.y &= 0x7FFF7FFFu;
            B3.u.z &= 0x7FFF7FFFu; B3.u.w &= 0x7FFF7FFFu;

            // ---- MFMA: D[hid 64][edge 16] ----
            floatx4 acc[4];
#pragma unroll
            for (int mt = 0; mt < 4; ++mt)
                acc[mt] = (floatx4){0.f, 0.f, 0.f, 0.f};
#pragma unroll
            for (int mt = 0; mt < 4; ++mt) {
                acc[mt] = __builtin_amdgcn_mfma_f32_16x16x32_f16(wf[mt][0], B0.h, acc[mt], 0, 0, 0);
                acc[mt] = __builtin_amdgcn_mfma_f32_16x16x32_f16(wf[mt][1], B1.h, acc[mt], 0, 0, 0);
                acc[mt] = __builtin_amdgcn_mfma_f32_16x16x32_f16(wf[mt][2], B2.h, acc[mt], 0, 0, 0);
                acc[mt] = __builtin_amdgcn_mfma_f32_16x16x32_f16(wf[mt][3], B3.h, acc[mt], 0, 0, 0);
            }

            // ---- epilogue: relu -> *W2 -> reduce over quads -> sigmoid ----
            float part = 0.f;
#pragma unroll
            for (int mt = 0; mt < 4; ++mt)
#pragma unroll
                for (int r = 0; r < 4; ++r)
                    part = fmaf(fmaxf(acc[mt][r] + (float)b1h[mt][r], 0.f),
                                (float)w2h[mt][r], part);
            part += __shfl_xor(part, 16, 64);
            part += __shfl_xor(part, 32, 64);
            if (L < 16)
                out[ebase + bt * 16 + L] = sigmoidf_(part + b2v);
        }
    }
}

// fallback / tail
__global__ void edge_naive(const float* __restrict__ x, const int* __restrict__ idx,
                           const float* __restrict__ W1, const float* __restrict__ b1,
                           const float* __restrict__ W2, const float* __restrict__ b2,
                           float* __restrict__ out, int n_edges, int start)
{
    int e = start + blockIdx.x * blockDim.x + threadIdx.x;
    if (e >= n_edges) return;
    int s = idx[e], d = idx[n_edges + e];
    float t = b2[0];
    for (int j = 0; j < HID; ++j) {
        float h = b1[j];
        for (int k = 0; k < DF; ++k)
            h = fmaf(fabsf(x[(size_t)s * DF + k] - x[(size_t)d * DF + k]), W1[(size_t)k * HID + j], h);
        t = fmaf(fmaxf(h, 0.f), W2[j], t);
    }
    out[e] = sigmoidf_(t);
}

extern "C" void kernel_launch(void* const* d_in, const int* in_sizes, int n_in,
                              void* d_out, int out_size, void* d_ws, size_t ws_size,
                              hipStream_t stream) {
    const float* x   = (const float*)d_in[0];
    const int*   idx = (const int*)d_in[1];
    const float* W1  = (const float*)d_in[2];
    const float* b1  = (const float*)d_in[3];
    const float* W2  = (const float*)d_in[4];
    const float* b2  = (const float*)d_in[5];
    float* out = (float*)d_out;

    const int n_edges = in_sizes[1] / 2;      // indices is [2, n_edges]
    const int n_x     = in_sizes[0];
    const int ngroups = n_edges / 256;        // 256 edges per block-tile
    const int rem     = n_edges - ngroups * 256;

    const size_t xh_bytes  = ((size_t)n_x * sizeof(_Float16) + 255) & ~(size_t)255;
    const size_t w1t_bytes = (size_t)DF * HID * sizeof(_Float16);
    const bool ok = (ws_size >= xh_bytes + w1t_bytes) && (n_x % 4 == 0);

    if (ok && ngroups > 0) {
        _Float16* xh  = (_Float16*)d_ws;
        _Float16* w1t = (_Float16*)((char*)d_ws + xh_bytes);
        const int n4 = n_x / 4;
        cvt_pre<<<(n4 + 255) / 256, 256, 0, stream>>>(x, W1, xh, w1t, n4);

        const int grid = ngroups < 768 ? ngroups : 768;   // 3 blocks/CU (no LDS cap)
        edge_mlp_v15<<<grid, 256, 0, stream>>>(xh, w1t, idx, b1, W2, b2,
                                               out, n_edges, ngroups, grid);
        if (rem > 0)
            edge_naive<<<(rem + 63) / 64, 64, 0, stream>>>(x, idx, W1, b1, W2, b2,
                                                           out, n_edges, ngroups * 256);
    } else {
        edge_naive<<<(n_edges + 63) / 64, 64, 0, stream>>>(x, idx, W1, b1, W2, b2,
                                                           out, n_edges, 0);
    }
}

// Round 8
// 94.677 us; speedup vs baseline: 1.1953x; 1.1953x over previous
//
#include <hip/hip_runtime.h>

// EdgeCompute v16 = v9 revert (best measured: 95.4us).
// out = sigmoid( relu(|x[s]-x[d]| @ W1 + b1) @ W2 + b2 )
// N_EDGES=640000, D_FEAT=128, HID=64.
//
// SESSION CONCLUSION (R1-R7 evidence):
//  - dur_us ~= 42us harness poison-fill (80% HBM peak, untouchable)
//    + ~24.5us edge kernel + cvt_pre + launch gaps.
//  - Edge kernel is at the L2 RANDOM-GATHER SERVICE-RATE floor:
//    1.28M row-gathers x 2 x 128B-line requests = 2.56M requests;
//    measured service rate ~44 lines/cyc chip-wide on TWO independent
//    kernels (v10: 2.56M/58.8k cyc = 43.5/cyc @ 24.5us; v15: 5.12M/114.5k
//    = 44.7/cyc @ 47.7us). Floor = 2.56M/44/2.4GHz = 24.3us = measured.
//  - R7 counters: FETCH 12.6MB (L2-resident, self-warming; no cold premium
//    across dispatches), MfmaUtil 7.7%, VALUBusy 18%, conflicts 0 -> no
//    pipe busy; request-rate bound confirmed.
//  - Dead levers: ILP depth (R2 null), 2x TLP (R4 null), L2 pre-warm (R6
//    null, self-warming), fp8 rows (R5: absmax 0.043 > 0.0196, cancellation
//    error irreducible by scaling), LDS-free direct-frag gather (R7: 64B
//    segments double request count, 2x slower), edge-sorting (scattered
//    out-writes add ~= requests saved).

#define DF 128
#define HID 64
#define AST 136   // halfs per LDS diff row (272 B = 17*16B)

typedef _Float16 half8   __attribute__((ext_vector_type(8)));
typedef _Float16 half4_t __attribute__((ext_vector_type(4)));
typedef float    floatx4 __attribute__((ext_vector_type(4)));

__device__ __forceinline__ float sigmoidf_(float t) {
    return __builtin_amdgcn_rcpf(1.0f + __expf(-t));
}

// pre-pass: x -> f16 (2.56MB, L2-resident), W1 -> f16 transposed [hid][feat]
__global__ void cvt_pre(const float* __restrict__ x, const float* __restrict__ W1,
                        _Float16* __restrict__ xh, _Float16* __restrict__ w1t, int n4)
{
    const int i = blockIdx.x * blockDim.x + threadIdx.x;
    if (i < n4) {
        float4 v = ((const float4*)x)[i];
        half4_t h = { (_Float16)v.x, (_Float16)v.y, (_Float16)v.z, (_Float16)v.w };
        ((half4_t*)xh)[i] = h;
    }
    if (i < DF * HID) {                      // w1t[h*128+f] = W1[f*64+h]
        const int h = i >> 7, f = i & 127;
        w1t[i] = (_Float16)W1[f * HID + h];
    }
}

#define ROW(idv) *(const half8*)(xh + (size_t)(idv) * DF + goff)

// issue 8 row loads (4 s-rows, 4 d-rows) for batch ids sIv/dIv
#define ISSUE(S, D, sIv, dIv)                                   \
    S##0 = ROW((sIv).x); S##1 = ROW((sIv).y);                   \
    S##2 = ROW((sIv).z); S##3 = ROW((sIv).w);                   \
    D##0 = ROW((dIv).x); D##1 = ROW((dIv).y);                   \
    D##2 = ROW((dIv).z); D##3 = ROW((dIv).w);

// |s - d| -> LDS rows (t*16 + q*4 + p), chunk r16
#define PROC(t, S, D) {                                                        \
    union { half8 h; uint4 u; } U0, U1, U2, U3;                                \
    U0.h = S##0 - D##0; U1.h = S##1 - D##1;                                    \
    U2.h = S##2 - D##2; U3.h = S##3 - D##3;                                    \
    U0.u.x &= 0x7FFF7FFFu; U0.u.y &= 0x7FFF7FFFu;                              \
    U0.u.z &= 0x7FFF7FFFu; U0.u.w &= 0x7FFF7FFFu;                              \
    U1.u.x &= 0x7FFF7FFFu; U1.u.y &= 0x7FFF7FFFu;                              \
    U1.u.z &= 0x7FFF7FFFu; U1.u.w &= 0x7FFF7FFFu;                              \
    U2.u.x &= 0x7FFF7FFFu; U2.u.y &= 0x7FFF7FFFu;                              \
    U2.u.z &= 0x7FFF7FFFu; U2.u.w &= 0x7FFF7FFFu;                              \
    U3.u.x &= 0x7FFF7FFFu; U3.u.y &= 0x7FFF7FFFu;                              \
    U3.u.z &= 0x7FFF7FFFu; U3.u.w &= 0x7FFF7FFFu;                              \
    *(half8*)(ldsw + ((t) * 16 + q * 4 + 0) * AST + goff) = U0.h;              \
    *(half8*)(ldsw + ((t) * 16 + q * 4 + 1) * AST + goff) = U1.h;              \
    *(half8*)(ldsw + ((t) * 16 + q * 4 + 2) * AST + goff) = U2.h;              \
    *(half8*)(ldsw + ((t) * 16 + q * 4 + 3) * AST + goff) = U3.h; }

__global__ __launch_bounds__(256, 2) void edge_mlp_v16(
    const _Float16* __restrict__ xh, const _Float16* __restrict__ w1t,
    const int* __restrict__ idx,
    const float* __restrict__ b1, const float* __restrict__ W2,
    const float* __restrict__ b2,
    float* __restrict__ out, int n_edges, int ngroups, int gstride)
{
    // per-wave diff tile: [64 edges][128 k (+8 pad)] f16 = 17.4KB x 4 waves
    __shared__ __attribute__((aligned(16))) _Float16 lds_d[4][64 * AST];

    const int tid = threadIdx.x;
    const int L   = tid & 63;
    const int r16 = L & 15;                 // frag-read: edge; gather: 16B chunk
    const int q   = L >> 4;                 // frag-read: quad; gather: row-in-quartet
    const int wv  = tid >> 6;
    _Float16* const ldsw = &lds_d[wv][0];

    // ---- A fragments: W1^T [hid=mt*16+r16][k=kb*32+q*8+j] (64 VGPRs) ----
    half8 wf[4][4];
#pragma unroll
    for (int mt = 0; mt < 4; ++mt)
#pragma unroll
        for (int kb = 0; kb < 4; ++kb)
            wf[mt][kb] = *(const half8*)(w1t + (size_t)(mt * 16 + r16) * DF + kb * 32 + q * 8);
#pragma unroll
    for (int mt = 0; mt < 4; ++mt)
#pragma unroll
        for (int kb = 0; kb < 4; ++kb)
            asm volatile("" : "+v"(wf[mt][kb]));

    // epilogue constants at hid = mt*16 + q*4 + r (f16-packed, 8 VGPRs)
    half4_t b1h[4], w2h[4];
#pragma unroll
    for (int mt = 0; mt < 4; ++mt)
#pragma unroll
        for (int r = 0; r < 4; ++r) {
            b1h[mt][r] = (_Float16)b1[mt * 16 + q * 4 + r];
            w2h[mt][r] = (_Float16)W2[mt * 16 + q * 4 + r];
        }
    const float b2v = b2[0];

    const int goff = r16 * 8;    // 16B chunk offset, shared by gather + LDS write
    const int idof = q * 4;      // this lane's 4 contiguous ids per 16-edge batch

    const int g0 = blockIdx.x;

    // ids for tile g0 (8 x int4; one 64B line per load)
    int4 sI0, sI1, sI2, sI3, dI0, dI1, dI2, dI3;
    {
        const int eb = g0 * 256 + wv * 64;
        sI0 = *(const int4*)(idx + eb +  0 + idof);
        sI1 = *(const int4*)(idx + eb + 16 + idof);
        sI2 = *(const int4*)(idx + eb + 32 + idof);
        sI3 = *(const int4*)(idx + eb + 48 + idof);
        dI0 = *(const int4*)(idx + n_edges + eb +  0 + idof);
        dI1 = *(const int4*)(idx + n_edges + eb + 16 + idof);
        dI2 = *(const int4*)(idx + n_edges + eb + 32 + idof);
        dI3 = *(const int4*)(idx + n_edges + eb + 48 + idof);
    }

#pragma unroll 1
    for (int g = g0; g < ngroups; g += gstride) {
        half8 sa0, sa1, sa2, sa3, da0, da1, da2, da3;   // buffer A
        half8 sb0, sb1, sb2, sb3, db0, db1, db2, db3;   // buffer B

        // batched gather: 1.5 batches in flight
        ISSUE(sa, da, sI0, dI0);
        ISSUE(sb, db, sI1, dI1);
        PROC(0, sa, da);
        ISSUE(sa, da, sI2, dI2);
        PROC(1, sb, db);
        ISSUE(sb, db, sI3, dI3);
        PROC(2, sa, da);

        // prefetch ids for the NEXT tile (arrive during MFMA/epilogue)
        int4 sN0, sN1, sN2, sN3, dN0, dN1, dN2, dN3;
        {
            int gn = g + gstride; if (gn >= ngroups) gn = g;
            const int ebn = gn * 256 + wv * 64;
            sN0 = *(const int4*)(idx + ebn +  0 + idof);
            sN1 = *(const int4*)(idx + ebn + 16 + idof);
            sN2 = *(const int4*)(idx + ebn + 32 + idof);
            sN3 = *(const int4*)(idx + ebn + 48 + idof);
            dN0 = *(const int4*)(idx + n_edges + ebn +  0 + idof);
            dN1 = *(const int4*)(idx + n_edges + ebn + 16 + idof);
            dN2 = *(const int4*)(idx + n_edges + ebn + 32 + idof);
            dN3 = *(const int4*)(idx + n_edges + ebn + 48 + idof);
        }

        PROC(3, sb, db);

        // ---- MFMA: D[hid 64][edge 64] = W1^T * diff ----
        floatx4 acc[4][4];                  // acc[mt][et]
#pragma unroll
        for (int mt = 0; mt < 4; ++mt)
#pragma unroll
            for (int et = 0; et < 4; ++et)
                acc[mt][et] = (floatx4){0.f, 0.f, 0.f, 0.f};
#pragma unroll
        for (int kb = 0; kb < 4; ++kb) {
#pragma unroll
            for (int et = 0; et < 4; ++et) {
                const half8 bf = *(const half8*)(ldsw + (et * 16 + r16) * AST + kb * 32 + q * 8);
                acc[0][et] = __builtin_amdgcn_mfma_f32_16x16x32_f16(wf[0][kb], bf, acc[0][et], 0, 0, 0);
                acc[1][et] = __builtin_amdgcn_mfma_f32_16x16x32_f16(wf[1][kb], bf, acc[1][et], 0, 0, 0);
                acc[2][et] = __builtin_amdgcn_mfma_f32_16x16x32_f16(wf[2][kb], bf, acc[2][et], 0, 0, 0);
                acc[3][et] = __builtin_amdgcn_mfma_f32_16x16x32_f16(wf[3][kb], bf, acc[3][et], 0, 0, 0);
            }
        }

        // advance id pipeline (row bufs dead; regs free)
        sI0 = sN0; sI1 = sN1; sI2 = sN2; sI3 = sN3;
        dI0 = dN0; dI1 = dN1; dI2 = dN2; dI3 = dN3;

        // ---- epilogue: relu -> *W2 -> reduce over quads -> sigmoid ----
#pragma unroll
        for (int et = 0; et < 4; ++et) {
            float part = 0.f;
#pragma unroll
            for (int mt = 0; mt < 4; ++mt)
#pragma unroll
                for (int r = 0; r < 4; ++r)
                    part = fmaf(fmaxf(acc[mt][et][r] + (float)b1h[mt][r], 0.f),
                                (float)w2h[mt][r], part);
            part += __shfl_xor(part, 16, 64);
            part += __shfl_xor(part, 32, 64);
            if (L < 16)
                out[g * 256 + wv * 64 + et * 16 + L] = sigmoidf_(part + b2v);
        }
    }
}

// fallback / tail
__global__ void edge_naive(const float* __restrict__ x, const int* __restrict__ idx,
                           const float* __restrict__ W1, const float* __restrict__ b1,
                           const float* __restrict__ W2, const float* __restrict__ b2,
                           float* __restrict__ out, int n_edges, int start)
{
    int e = start + blockIdx.x * blockDim.x + threadIdx.x;
    if (e >= n_edges) return;
    int s = idx[e], d = idx[n_edges + e];
    float t = b2[0];
    for (int j = 0; j < HID; ++j) {
        float h = b1[j];
        for (int k = 0; k < DF; ++k)
            h = fmaf(fabsf(x[(size_t)s * DF + k] - x[(size_t)d * DF + k]), W1[(size_t)k * HID + j], h);
        t = fmaf(fmaxf(h, 0.f), W2[j], t);
    }
    out[e] = sigmoidf_(t);
}

extern "C" void kernel_launch(void* const* d_in, const int* in_sizes, int n_in,
                              void* d_out, int out_size, void* d_ws, size_t ws_size,
                              hipStream_t stream) {
    const float* x   = (const float*)d_in[0];
    const int*   idx = (const int*)d_in[1];
    const float* W1  = (const float*)d_in[2];
    const float* b1  = (const float*)d_in[3];
    const float* W2  = (const float*)d_in[4];
    const float* b2  = (const float*)d_in[5];
    float* out = (float*)d_out;

    const int n_edges = in_sizes[1] / 2;      // indices is [2, n_edges]
    const int n_x     = in_sizes[0];
    const int ngroups = n_edges / 256;        // 256 edges per block-tile
    const int rem     = n_edges - ngroups * 256;

    const size_t xh_bytes  = ((size_t)n_x * sizeof(_Float16) + 255) & ~(size_t)255;
    const size_t w1t_bytes = (size_t)DF * HID * sizeof(_Float16);
    const bool ok = (ws_size >= xh_bytes + w1t_bytes) && (n_x % 4 == 0);

    if (ok && ngroups > 0) {
        _Float16* xh  = (_Float16*)d_ws;
        _Float16* w1t = (_Float16*)((char*)d_ws + xh_bytes);
        const int n4 = n_x / 4;
        cvt_pre<<<(n4 + 255) / 256, 256, 0, stream>>>(x, W1, xh, w1t, n4);

        const int grid = ngroups < 512 ? ngroups : 512;   // 2 blocks/CU
        edge_mlp_v16<<<grid, 256, 0, stream>>>(xh, w1t, idx, b1, W2, b2,
                                               out, n_edges, ngroups, grid);
        if (rem > 0)
            edge_naive<<<(rem + 63) / 64, 64, 0, stream>>>(x, idx, W1, b1, W2, b2,
                                                           out, n_edges, ngroups * 256);
    } else {
        edge_naive<<<(n_edges + 63) / 64, 64, 0, stream>>>(x, idx, W1, b1, W2, b2,
                                                           out, n_edges, 0);
    }
}